// Round 1
// baseline (350.542 us; speedup 1.0000x reference)
//
#include <hip/hip_runtime.h>

// MeanSquaredError3: heatmap MSE (d1) + offset-regression MSE (d2), scalar out.
//
// Strategy: memory-bound. Dense read of h = out[:, :14] (89.9 MB); the o-planes
// (179.8 MB) are only gathered at 2 floats per (b,j) -> ~15 MB of granule
// traffic. One wave per (b,j): float4-coalesced h load (49 lanes x 16B = 784B),
// wave argmax, lane-0 scalar tail, Gaussian tt from a 196-float LDS table.
// Global reduction: wave shuffle -> block LDS -> fp64 hw atomics into 16
// contention-spread slots -> tiny finish kernel.

#define COL 14
#define NJ 14
#define CELLS (COL * COL)     // 196
#define THREADS 256
#define WPB (THREADS / 64)    // waves per block = 4
#define BLOCKS 2048           // 8192 waves = 32/CU; 114688 pairs / 8192 = 14 per wave
#define NSLOT 16              // accumulator spread (atomic contention / 16)

__global__ __launch_bounds__(THREADS)
void mse3_main(const float* __restrict__ outp, const float* __restrict__ tp,
               const float* __restrict__ vp, double* __restrict__ acc, int npair)
{
    __shared__ float Gs[CELLS];
    __shared__ float cminS[COL], cmaxS[COL];
    __shared__ double part[WPB][4];

    const int tid = threadIdx.x;

    // Build G exactly like the reference: w = exp(-0.5*k^2) fp64, normalized,
    // symmetric-padded identity convolution, accumulated in fp64, cast to f32.
    if (tid < CELLS) {
        const double wraw[9] = {3.3546262790251185e-4, 1.1108996538242306e-2,
                                1.353352832366127e-1,  6.065306597126334e-1, 1.0,
                                6.065306597126334e-1,  1.353352832366127e-1,
                                1.1108996538242306e-2, 3.3546262790251185e-4};
        const double Z = 2.5066208042307818;  // sum of wraw
        int gi = tid / COL;
        int gj = tid - COL * gi;
        double a = 0.0;
#pragma unroll
        for (int k = 0; k < 9; ++k) {
            int r = gi + k;  // row into symmetric-padded eye (22 rows)
            int m = (r < 4) ? (3 - r) : ((r < 18) ? (r - 4) : (31 - r));
            if (m == gj) a += wraw[k] / Z;
        }
        Gs[tid] = (float)a;
    }
    __syncthreads();
    // Per-column min/max of G (all entries > 0, so min/max of the outer
    // product tt = gy[y]*gx[x] factorize; fp multiply is monotone so the
    // factored fp32 result equals elementwise min/max of the fp32 products).
    if (tid < COL) {
        float mn = Gs[tid], mx = mn;
        for (int r = 1; r < COL; ++r) {
            float g = Gs[r * COL + tid];
            mn = fminf(mn, g);
            mx = fmaxf(mx, g);
        }
        cminS[tid] = mn;
        cmaxS[tid] = mx;
    }
    __syncthreads();

    const int lane  = tid & 63;
    const int gwave = blockIdx.x * WPB + (tid >> 6);
    const int nwaves = BLOCKS * WPB;

    float s1 = 0.0f;                        // per-lane diff1^2 partial
    float s2 = 0.0f, cnt = 0.0f, n2 = 0.0f; // lane-0-only partials

    for (int p = gwave; p < npair; p += nwaves) {
        const int b = p / NJ;
        const int j = p - NJ * b;
        const float* hptr = outp + ((size_t)b * (3 * NJ) + j) * CELLS;

        // --- coalesced h load: 49 lanes x float4 = 196 floats (784B) ---
        float4 hv = make_float4(0.f, 0.f, 0.f, 0.f);
        float best = -3.402823466e38f;
        int bidx = 0;
        if (lane < 49) {
            hv = reinterpret_cast<const float4*>(hptr)[lane];
            best = hv.x; bidx = 4 * lane;
            if (hv.y > best) { best = hv.y; bidx = 4 * lane + 1; }
            if (hv.z > best) { best = hv.z; bidx = 4 * lane + 2; }
            if (hv.w > best) { best = hv.w; bidx = 4 * lane + 3; }
        }
        // wave argmax, first-occurrence tie-break (lower index wins)
#pragma unroll
        for (int off = 32; off >= 1; off >>= 1) {
            float ov = __shfl_down(best, off, 64);
            int   oi = __shfl_down(bidx, off, 64);
            if (ov > best || (ov == best && oi < bidx)) { best = ov; bidx = oi; }
        }
        const int idx = __shfl(bidx, 0, 64);

        // --- lane 0: sparse o gather + t/v scalar tail ---
        int pack = 0;
        if (lane == 0) {
            float ox = hptr[NJ * CELLS + idx];        // out[b, 14+j, idx]
            float oy = hptr[2 * NJ * CELLS + idx];    // out[b, 28+j, idx]
            float2 tv = reinterpret_cast<const float2*>(tp)[p];
            float2 vv = reinterpret_cast<const float2*>(vp)[p];
            int xi = (int)(tv.x * 14.0f);             // trunc toward 0, as astype(int32)
            int yi = (int)(tv.y * 14.0f);
            bool inb  = (xi >= 0) && (xi <= COL - 1) && (yi >= 0) && (yi <= COL - 1);
            bool vis  = ((int)vv.x == 1);
            bool scat = vis && inb;
            float ve0 = (vis && !inb) ? 0.0f : vv.x;
            float ve1 = (vis && !inb) ? 0.0f : vv.y;
            bool vise = ((int)ve0 == 1);
            int yc = idx / COL;
            int xc = idx - COL * yc;
            const float SCALE = (float)(1.0 / 14.0);
            float dx = (ox + (float)xc) * SCALE - tv.x;
            float dy = (oy + (float)yc) * SCALE - tv.y;
            dx *= ve0;
            dy *= ve1;
            s2 += dx * dx + dy * dy;
            if (vise) cnt += 1.0f;
            n2 += ve0 + ve1;
            int xic = min(max(xi, 0), COL - 1);
            int yic = min(max(yi, 0), COL - 1);
            pack = xic | (yic << 4) | (scat ? 256 : 0) | (vise ? 512 : 0);
        }
        pack = __shfl(pack, 0, 64);
        const int  xic  = pack & 15;
        const int  yic  = (pack >> 4) & 15;
        const bool scat = (pack & 256) != 0;
        const bool vise = (pack & 512) != 0;

        // --- diff1 = h - tt, row-0 vis mask, accumulate squares ---
        if (lane < 49) {
            float h4[4] = {hv.x, hv.y, hv.z, hv.w};
            int e0 = 4 * lane;
            int y = e0 / COL;
            int x = e0 - COL * y;
            if (scat) {
                float mn  = cminS[yic] * cminS[xic];
                float mx  = cmaxS[yic] * cmaxS[xic];
                float inv = 1.0f / (mx - mn);
#pragma unroll
                for (int c = 0; c < 4; ++c) {
                    float tt = (Gs[y * COL + yic] * Gs[x * COL + xic] - mn) * inv;
                    float d = h4[c] - tt;
                    if (y == 0 && !vise) d = 0.0f;
                    s1 += d * d;
                    ++x; if (x == COL) { x = 0; ++y; }
                }
            } else {
#pragma unroll
                for (int c = 0; c < 4; ++c) {
                    float d = h4[c];
                    if (y == 0 && !vise) d = 0.0f;
                    s1 += d * d;
                    ++x; if (x == COL) { x = 0; ++y; }
                }
            }
        }
    }

    // --- wave -> block -> global reduction ---
#pragma unroll
    for (int off = 32; off >= 1; off >>= 1) s1 += __shfl_down(s1, off, 64);

    const int w = tid >> 6;
    if (lane == 0) {
        part[w][0] = (double)s1;
        part[w][1] = (double)s2;
        part[w][2] = (double)cnt;
        part[w][3] = (double)n2;
    }
    __syncthreads();
    if (tid == 0) {
        double a0 = 0, a1 = 0, a2 = 0, a3 = 0;
        for (int i = 0; i < WPB; ++i) {
            a0 += part[i][0]; a1 += part[i][1];
            a2 += part[i][2]; a3 += part[i][3];
        }
        double* slot = acc + (size_t)(blockIdx.x & (NSLOT - 1)) * 4;
        unsafeAtomicAdd(&slot[0], a0);  // hw global_atomic_add_f64
        unsafeAtomicAdd(&slot[1], a1);
        unsafeAtomicAdd(&slot[2], a2);
        unsafeAtomicAdd(&slot[3], a3);
    }
}

__global__ void mse3_final(const double* __restrict__ acc, float* __restrict__ o)
{
    double s1 = 0, s2 = 0, cnt = 0, n2 = 0;
    for (int i = 0; i < NSLOT; ++i) {
        s1  += acc[i * 4 + 0];
        s2  += acc[i * 4 + 1];
        cnt += acc[i * 4 + 2];
        n2  += acc[i * 4 + 3];
    }
    // d1 + d2; reference n2 = v_eff.sum()/2
    o[0] = (float)(s1 / cnt + s2 / (0.5 * n2));
}

extern "C" void kernel_launch(void* const* d_in, const int* in_sizes, int n_in,
                              void* d_out, int out_size, void* d_ws, size_t ws_size,
                              hipStream_t stream)
{
    const float* outp = (const float*)d_in[0];   // (B, 42, 14, 14) f32
    const float* tp   = (const float*)d_in[1];   // (B, 14, 2) f32
    const float* vp   = (const float*)d_in[2];   // (B, 14, 2) f32
    double* acc = (double*)d_ws;                 // NSLOT*4 doubles = 512 B

    const int B = in_sizes[0] / (3 * NJ * CELLS);
    const int npair = B * NJ;

    hipMemsetAsync(d_ws, 0, NSLOT * 4 * sizeof(double), stream);
    mse3_main<<<BLOCKS, THREADS, 0, stream>>>(outp, tp, vp, acc, npair);
    mse3_final<<<1, 1, 0, stream>>>(acc, (float*)d_out);
}

// Round 2
// 331.832 us; speedup vs baseline: 1.0564x; 1.0564x over previous
//
#include <hip/hip_runtime.h>

// MeanSquaredError3: heatmap MSE (d1) + offset-regression MSE (d2), scalar out.
//
// Round 2: memory-bound restructure for MLP. Round 1 had two serialized HBM
// round-trips per (b,j) iteration (h load -> argmax -> lane0 gather of
// ox/oy + t/v) ~= 2000 dependent cycles x 14 iters -> ~140us vs ~17us roofline.
// Now: phase 0 batches all t/v loads across lanes (1 round trip / 14 pairs),
// the loop only streams h with a +1 prefetch (always one load in flight),
// and the ox/oy gathers are deferred: per-pair argmax idx is kept in a
// lane-indexed register and all 28 gathers issue together after the loop.
// Reduction: wave shuffle -> block LDS -> deterministic per-block partials in
// d_ws (no atomics, no memset) -> 256-thread finish kernel.

#define COL 14
#define NJ 14
#define CELLS (COL * COL)     // 196
#define THREADS 256
#define WPB (THREADS / 64)    // 4 waves per block
#define BLOCKS 2048           // 8192 waves = 32/CU; 114688 pairs -> 14 per wave
#define MAXI 16               // max pairs per wave per super-iteration (<= 64)
#define NEGINF -3.402823466e38f

__global__ __launch_bounds__(THREADS)
void mse3_main(const float* __restrict__ outp, const float* __restrict__ tp,
               const float* __restrict__ vp, double* __restrict__ partial, int npair)
{
    __shared__ float Gs[CELLS];
    __shared__ float cminS[COL], cmaxS[COL];
    __shared__ double part[WPB][4];

    const int tid = threadIdx.x;

    // Build G exactly like the reference: w = exp(-0.5*k^2) fp64, normalized,
    // symmetric-padded identity convolution, accumulated fp64, cast to f32.
    if (tid < CELLS) {
        const double wraw[9] = {3.3546262790251185e-4, 1.1108996538242306e-2,
                                1.353352832366127e-1,  6.065306597126334e-1, 1.0,
                                6.065306597126334e-1,  1.353352832366127e-1,
                                1.1108996538242306e-2, 3.3546262790251185e-4};
        const double Z = 2.5066208042307818;  // sum of wraw
        int gi = tid / COL;
        int gj = tid - COL * gi;
        double a = 0.0;
#pragma unroll
        for (int k = 0; k < 9; ++k) {
            int r = gi + k;  // row into symmetric-padded eye (22 rows)
            int m = (r < 4) ? (3 - r) : ((r < 18) ? (r - 4) : (31 - r));
            if (m == gj) a += wraw[k] / Z;
        }
        Gs[tid] = (float)a;
    }
    __syncthreads();
    // Per-column min/max (all G entries > 0: outer-product min/max factorize;
    // fp multiply is monotone, so factored fp32 min/max == elementwise).
    if (tid < COL) {
        float mn = Gs[tid], mx = mn;
        for (int r = 1; r < COL; ++r) {
            float g = Gs[r * COL + tid];
            mn = fminf(mn, g);
            mx = fmaxf(mx, g);
        }
        cminS[tid] = mn;
        cmaxS[tid] = mx;
    }
    __syncthreads();

    const int lane   = tid & 63;
    const int wv     = tid >> 6;
    const int gwave  = blockIdx.x * WPB + wv;
    const int nwaves = BLOCKS * WPB;

    float s1 = 0.0f, s2 = 0.0f, cnt = 0.0f, n2 = 0.0f;

    for (int pbase = gwave; pbase < npair; pbase += nwaves * MAXI) {
        const int m = min(MAXI, (npair - pbase + nwaves - 1) / nwaves);

        // --- phase 0: batched t/v loads, one pair per lane ---
        int packreg = 0;
        float tvx = 0.f, tvy = 0.f, vvx = 0.f, vvy = 0.f;
        if (lane < m) {
            int p = pbase + lane * nwaves;
            float2 tv = reinterpret_cast<const float2*>(tp)[p];
            float2 vv = reinterpret_cast<const float2*>(vp)[p];
            tvx = tv.x; tvy = tv.y; vvx = vv.x; vvy = vv.y;
            int xi = (int)(tv.x * 14.0f);   // trunc toward 0, as astype(int32)
            int yi = (int)(tv.y * 14.0f);
            bool inb    = (xi >= 0) && (xi <= COL - 1) && (yi >= 0) && (yi <= COL - 1);
            bool vis    = ((int)vv.x == 1);
            bool scat   = vis && inb;
            bool zeroed = vis && !inb;
            float ve0   = zeroed ? 0.0f : vv.x;
            bool vise   = ((int)ve0 == 1);
            int xic = min(max(xi, 0), COL - 1);
            int yic = min(max(yi, 0), COL - 1);
            packreg = xic | (yic << 4) | (scat ? 256 : 0) | (vise ? 512 : 0)
                          | (zeroed ? 1024 : 0);
        }

        // --- prefetch first h tile (49 lanes x float4 = 784 B) ---
        float4 hv_next = make_float4(0.f, 0.f, 0.f, 0.f);
        if (lane < 49) {
            int b = pbase / NJ, j = pbase - NJ * b;
            hv_next = reinterpret_cast<const float4*>(
                outp + ((size_t)b * (3 * NJ) + j) * CELLS)[lane];
        }

        int myidx = 0;  // lane i keeps argmax idx of its pair i
        for (int i = 0; i < m; ++i) {
            float4 hv = hv_next;
            if (i + 1 < m && lane < 49) {       // +1 prefetch: only in-loop memory op
                int p = pbase + (i + 1) * nwaves;
                int b = p / NJ, j = p - NJ * b;
                hv_next = reinterpret_cast<const float4*>(
                    outp + ((size_t)b * (3 * NJ) + j) * CELLS)[lane];
            }
            const int pk = __shfl(packreg, i, 64);
            const int xic = pk & 15;
            const int yic = (pk >> 4) & 15;
            const bool scat = (pk & 256) != 0;
            const bool vise = (pk & 512) != 0;

            // wave argmax, first-occurrence tie-break
            float best = NEGINF;
            int bidx = 0;
            if (lane < 49) {
                best = hv.x; bidx = 4 * lane;
                if (hv.y > best) { best = hv.y; bidx = 4 * lane + 1; }
                if (hv.z > best) { best = hv.z; bidx = 4 * lane + 2; }
                if (hv.w > best) { best = hv.w; bidx = 4 * lane + 3; }
            }
#pragma unroll
            for (int off = 32; off >= 1; off >>= 1) {
                float ov = __shfl_down(best, off, 64);
                int   oi = __shfl_down(bidx, off, 64);
                if (ov > best || (ov == best && oi < bidx)) { best = ov; bidx = oi; }
            }
            const int idxb = __shfl(bidx, 0, 64);
            if (lane == i) myidx = idxb;

            // s1 += (h - tt)^2 with row-0 visibility mask
            if (lane < 49) {
                float h4[4] = {hv.x, hv.y, hv.z, hv.w};
                int y = (4 * lane) / COL;
                int x = 4 * lane - COL * y;
                if (scat) {
                    float mn  = cminS[yic] * cminS[xic];
                    float mx  = cmaxS[yic] * cmaxS[xic];
                    float inv = 1.0f / (mx - mn);
#pragma unroll
                    for (int c = 0; c < 4; ++c) {
                        float tt = (Gs[y * COL + yic] * Gs[x * COL + xic] - mn) * inv;
                        float d = h4[c] - tt;
                        if (y == 0 && !vise) d = 0.0f;
                        s1 += d * d;
                        ++x; if (x == COL) { x = 0; ++y; }
                    }
                } else {
#pragma unroll
                    for (int c = 0; c < 4; ++c) {
                        float d = h4[c];
                        if (y == 0 && !vise) d = 0.0f;
                        s1 += d * d;
                        ++x; if (x == COL) { x = 0; ++y; }
                    }
                }
            }
        }

        // --- phase 2: all ox/oy gathers at once (full MLP, one round trip) ---
        if (lane < m) {
            int p = pbase + lane * nwaves;
            int b = p / NJ, j = p - NJ * b;
            const float* base = outp + (size_t)b * (3 * NJ) * CELLS;
            float ox = base[(size_t)(NJ + j) * CELLS + myidx];
            float oy = base[(size_t)(2 * NJ + j) * CELLS + myidx];
            bool zeroed = (packreg & 1024) != 0;
            bool vise   = (packreg & 512) != 0;
            float ve0 = zeroed ? 0.0f : vvx;
            float ve1 = zeroed ? 0.0f : vvy;
            int yc = myidx / COL;
            int xc = myidx - COL * yc;
            const float SC = (float)(1.0 / 14.0);
            float dx = (ox + (float)xc) * SC - tvx; dx *= ve0;
            float dy = (oy + (float)yc) * SC - tvy; dy *= ve1;
            s2 += dx * dx + dy * dy;
            if (vise) cnt += 1.0f;
            n2 += ve0 + ve1;
        }
    }

    // --- wave -> block reduction, deterministic per-block partials ---
#pragma unroll
    for (int off = 32; off >= 1; off >>= 1) {
        s1  += __shfl_down(s1,  off, 64);
        s2  += __shfl_down(s2,  off, 64);
        cnt += __shfl_down(cnt, off, 64);
        n2  += __shfl_down(n2,  off, 64);
    }
    if (lane == 0) {
        part[wv][0] = (double)s1;
        part[wv][1] = (double)s2;
        part[wv][2] = (double)cnt;
        part[wv][3] = (double)n2;
    }
    __syncthreads();
    if (tid == 0) {
        double a0 = 0, a1 = 0, a2 = 0, a3 = 0;
        for (int i = 0; i < WPB; ++i) {
            a0 += part[i][0]; a1 += part[i][1];
            a2 += part[i][2]; a3 += part[i][3];
        }
        double* o = partial + (size_t)blockIdx.x * 4;
        o[0] = a0; o[1] = a1; o[2] = a2; o[3] = a3;
    }
}

__global__ __launch_bounds__(256)
void mse3_final(const double* __restrict__ partial, float* __restrict__ o)
{
    __shared__ double p2[4][4];
    double a0 = 0, a1 = 0, a2 = 0, a3 = 0;
    for (int b = threadIdx.x; b < BLOCKS; b += 256) {
        const double* q = partial + (size_t)b * 4;
        a0 += q[0]; a1 += q[1]; a2 += q[2]; a3 += q[3];
    }
#pragma unroll
    for (int off = 32; off >= 1; off >>= 1) {
        a0 += __shfl_down(a0, off, 64);
        a1 += __shfl_down(a1, off, 64);
        a2 += __shfl_down(a2, off, 64);
        a3 += __shfl_down(a3, off, 64);
    }
    const int lane = threadIdx.x & 63, wv = threadIdx.x >> 6;
    if (lane == 0) { p2[wv][0] = a0; p2[wv][1] = a1; p2[wv][2] = a2; p2[wv][3] = a3; }
    __syncthreads();
    if (threadIdx.x == 0) {
        double s1 = 0, s2 = 0, cn = 0, nn = 0;
        for (int i = 0; i < 4; ++i) {
            s1 += p2[i][0]; s2 += p2[i][1]; cn += p2[i][2]; nn += p2[i][3];
        }
        o[0] = (float)(s1 / cn + s2 / (0.5 * nn));  // d1 + d2
    }
}

extern "C" void kernel_launch(void* const* d_in, const int* in_sizes, int n_in,
                              void* d_out, int out_size, void* d_ws, size_t ws_size,
                              hipStream_t stream)
{
    const float* outp = (const float*)d_in[0];   // (B, 42, 14, 14) f32
    const float* tp   = (const float*)d_in[1];   // (B, 14, 2) f32
    const float* vp   = (const float*)d_in[2];   // (B, 14, 2) f32
    double* partial = (double*)d_ws;             // BLOCKS*4 doubles = 64 KB

    const int B = in_sizes[0] / (3 * NJ * CELLS);
    const int npair = B * NJ;

    mse3_main<<<BLOCKS, THREADS, 0, stream>>>(outp, tp, vp, partial, npair);
    mse3_final<<<1, 256, 0, stream>>>(partial, (float*)d_out);
}